// Round 8
// baseline (165.340 us; speedup 1.0000x reference)
//
#include <hip/hip_runtime.h>
#include <math.h>

#define HAND_PARAM_DIM 32
#define INF_DIST 1000000.0f
#define EPS 1e-8f
#define NROW 64        // B*S
#define HW_N 65536
#define NV 778
#define NMESH 1556
#define NMESH_PAD 1568  // 16 slices * 98
#define SLICE 98
#define NSLICE 16
#define K_SEL 1024u
#define HALF_BITS  0x3F000000u  // bits of 0.5f
#define GUESS_BITS 0x3F733333u  // bits of 0.95f (speculative collect threshold)
#define W_CAP 512               // per-wave candidate cap (pow2; mean 205, +22 sigma)
#define NWAVE 16
#define FIX_SCALE 4294967296.0  // 2^32 fixed-point scale

// ---- workspace layout (bytes) ----
#define OFF_MESH 0u             // 64*1568*16  = 1605632
#define OFF_SAMP 1605632u       // 64*1024*16  = 1048576
#define OFF_MINP 2654208u       // 64*16*1024*4 = 4194304
#define OFF_CTR  6848512u       // 4 u32: gsum(2), gcnt, done (8-aligned)

typedef unsigned long long u64;

// ---------------------------------------------------------------------------
// Kernel 1: per-row prep. 64 blocks x 1024 threads. Everything row-local:
//  (a) MANO mesh -> meshP (pre-scaled: m.xyz=-2p, m.w=|p|^2; pads w=+inf)
//  (b) one mask pass collecting candidates >=0.95 into per-wave LDS segments
//  (c) exact top-1024 via 2-phase radix on (bits-GUESS) (16-bit range),
//      lowest-index tie cut; generic 4-phase global fallback for anomalies
//  (d) gather means -> sampbuf[row][i] = (x,y,z, val>0.5 ? |s|^2 : -1)
// Block 0 also zeroes the reduce counters.
// ---------------------------------------------------------------------------
__global__ void __launch_bounds__(1024) prep_kernel(
    const float* __restrict__ mask, const float* __restrict__ means,
    const int* __restrict__ hv, const float* __restrict__ hp,
    const float* __restrict__ vtl, const float* __restrict__ vtr,
    const float* __restrict__ sdl, const float* __restrict__ sdr,
    const float* __restrict__ pdl, const float* __restrict__ pdr,
    float4* __restrict__ meshP, float4* __restrict__ sampbuf,
    unsigned* __restrict__ ctr)
{
    __shared__ u64 cl[NWAVE * W_CAP];          // 64 KB candidate segments
    __shared__ unsigned wcnt[NWAVE], wsel[NWAVE], wpos[NWAVE];
    __shared__ unsigned h[256], seg[256];
    __shared__ unsigned tlist[256];
    __shared__ unsigned sbin, sRn, sbad, stot, tn, scut;

    int row = blockIdx.x, t = threadIdx.x;
    int wave = t >> 6;

    if (row == 0 && t < 4) ctr[t] = 0u;        // gsum lo/hi, gcnt, done
    sampbuf[(size_t)row * K_SEL + t] = make_float4(0.f, 0.f, 0.f, -1.0f);
    int hv0 = hv[row*2], hv1 = hv[row*2+1];
    if (!(hv0 | hv1)) return;

    // ---------------- (a) mesh ----------------
    for (int slot = t; slot < NMESH_PAD; slot += 1024) {
        if (slot >= NMESH) {
            meshP[row * NMESH_PAD + slot] = make_float4(0.f, 0.f, 0.f, 3.4e38f);
            continue;
        }
        int hand = (slot >= NV) ? 1 : 0;
        int v = slot - hand * NV;
        const float* p = hp + row * (2 * HAND_PARAM_DIM) + hand * HAND_PARAM_DIM;
        int valid = hand ? hv1 : hv0;
        const float* vt = hand ? vtr : vtl;
        const float* sd = hand ? sdr : sdl;
        const float* pd = hand ? pdr : pdl;

        float tx = p[0], ty = p[1], tz = p[2];
        float q0 = p[3], q1 = p[4], q2 = p[5], q3 = p[6];
        float qn = sqrtf(q0*q0 + q1*q1 + q2*q2 + q3*q3 + EPS);
        float inv = 1.0f / fmaxf(qn, EPS);
        q0 *= inv; q1 *= inv; q2 *= inv; q3 *= inv;
        float sgn = (q0 < 0.0f) ? -1.0f : 1.0f;
        q0 *= sgn; q1 *= sgn; q2 *= sgn; q3 *= sgn;
        float sin_half = sqrtf(q1*q1 + q2*q2 + q3*q3 + EPS);
        float w_safe = fminf(fmaxf(q0, -1.0f + EPS), 1.0f - EPS);
        float ang2 = 2.0f * atan2f(sin_half, w_safe);
        float factor = (sin_half < 1e-6f) ? 2.0f : ang2 / fmaxf(sin_half, EPS);
        float rx = q1 * factor, ry = q2 * factor, rz = q3 * factor;
        float ang = sqrtf(rx*rx + ry*ry + rz*rz + EPS);
        float iang = 1.0f / ang;
        float ax = rx * iang, ay = ry * iang, az = rz * iang;
        float c = cosf(ang), s = sinf(ang), omc = 1.0f - c;

        float px = vt[v*3+0], py = vt[v*3+1], pz = vt[v*3+2];
        const float* sdv = sd + v * 30;
#pragma unroll
        for (int k = 0; k < 10; k++) {
            float b = p[22 + k];
            px = fmaf(sdv[k],      b, px);
            py = fmaf(sdv[10 + k], b, py);
            pz = fmaf(sdv[20 + k], b, pz);
        }
        const float* pdv = pd + v * 45;
#pragma unroll
        for (int k = 0; k < 15; k++) {
            float o = p[7 + k];
            px = fmaf(pdv[k],      o, px);
            py = fmaf(pdv[15 + k], o, py);
            pz = fmaf(pdv[30 + k], o, pz);
        }
        float cx = ay * pz - az * py;
        float cy = az * px - ax * pz;
        float cz = ax * py - ay * px;
        float kdv = ax * px + ay * py + az * pz;
        float ox = px * c + cx * s + ax * kdv * omc + tx;
        float oy = py * c + cy * s + ay * kdv * omc + ty;
        float oz = pz * c + cz * s + az * kdv * omc + tz;
        if (!valid) { ox = INF_DIST; oy = INF_DIST; oz = INF_DIST; }
        float sb = fmaf(ox, ox, fmaf(oy, oy, oz * oz));
        meshP[row * NMESH_PAD + slot] = make_float4(-2.0f*ox, -2.0f*oy, -2.0f*oz, sb);
    }

    // ---------------- (b) collect ----------------
    if (t < NWAVE) wcnt[t] = 0u;
    if (t == 0) { sbad = 0u; tn = 0u; }
    __syncthreads();
    const float* mrow = mask + (size_t)row * HW_N;
    const float4* m4 = (const float4*)mrow;
#pragma unroll 4
    for (int k = 0; k < 16; k++) {
        float4 v = m4[k * 1024 + t];
        unsigned e0 = (unsigned)((k * 1024 + t) * 4);
        unsigned u;
#define PROC(comp, off_) { u = __float_as_uint(comp); \
        if (u - GUESS_BITS < 0x10000u) { \
            unsigned p_ = atomicAdd(&wcnt[wave], 1u); \
            if (p_ < W_CAP) cl[(wave << 9) + p_] = ((u64)u << 32) | (e0 + off_); \
        } else if (u >= GUESS_BITS + 0x10000u && u < 0x80000000u) sbad = 1u; }
        PROC(v.x, 0u) PROC(v.y, 1u) PROC(v.z, 2u) PROC(v.w, 3u)
#undef PROC
    }
    __syncthreads();
    if (t == 0) {
        unsigned run = 0;
#pragma unroll
        for (int c2 = 0; c2 < NWAVE; c2++) {
            unsigned n = wcnt[c2];
            if (n > W_CAP) { sbad = 1u; n = W_CAP; wcnt[c2] = n; }
            run += n;
        }
        stot = run;
    }
    __syncthreads();
    bool ok = (sbad == 0u) && (stot >= K_SEL);

    // ---------------- (c) exact threshold ----------------
    unsigned T, R;
    if (ok) {
        unsigned pfx = 0u; R = K_SEL;
        for (int ph = 0; ph < 2; ph++) {
            if (t < 256) h[t] = 0u;
            __syncthreads();
            for (int i = t; i < NWAVE * W_CAP; i += 1024) {
                if ((unsigned)(i & (W_CAP - 1)) < wcnt[i >> 9]) {
                    unsigned off = (unsigned)(cl[i] >> 32) - GUESS_BITS;
                    if (ph == 0) atomicAdd(&h[off >> 8], 1u);
                    else if ((off >> 8) == pfx) atomicAdd(&h[off & 0xFFu], 1u);
                }
            }
            __syncthreads();
            if (t < 256) seg[t] = h[t];
            __syncthreads();
            for (int o = 1; o < 256; o <<= 1) {        // inclusive suffix scan
                unsigned v = 0u;
                if (t < 256 && t + o < 256) v = seg[t + o];
                __syncthreads();
                if (t < 256) seg[t] += v;
                __syncthreads();
            }
            if (t < 256) {
                unsigned excl = (t < 255) ? seg[t + 1] : 0u;
                if (excl < R && R <= seg[t]) { sbin = (unsigned)t; sRn = R - excl; }
            }
            __syncthreads();
            pfx = (ph == 0) ? sbin : ((pfx << 8) | sbin);
            R = sRn;
            __syncthreads();
        }
        T = GUESS_BITS + pfx;
    } else {
        unsigned pfx = 0u; R = K_SEL;
        for (int ph = 0; ph < 4; ph++) {
            int sh = 24 - 8 * ph;
            unsigned pm = (ph == 0) ? 0u : (0xFFFFFFFFu << (sh + 8));
            if (t < 256) h[t] = 0u;
            __syncthreads();
            for (int i = t; i < HW_N; i += 1024) {
                unsigned u = __float_as_uint(mrow[i]);
                if ((u & pm) == pfx) atomicAdd(&h[(u >> sh) & 0xFFu], 1u);
            }
            __syncthreads();
            if (t < 256) seg[t] = h[t];
            __syncthreads();
            for (int o = 1; o < 256; o <<= 1) {
                unsigned v = 0u;
                if (t < 256 && t + o < 256) v = seg[t + o];
                __syncthreads();
                if (t < 256) seg[t] += v;
                __syncthreads();
            }
            if (t < 256) {
                unsigned excl = (t < 255) ? seg[t + 1] : 0u;
                if (excl < R && R <= seg[t]) { sbin = (unsigned)t; sRn = R - excl; }
            }
            __syncthreads();
            pfx |= sbin << sh;
            R = sRn;
            __syncthreads();
        }
        T = pfx;
    }

    // ties at exact value T -> R-th smallest index is the cut
    if (ok) {
        for (int i = t; i < NWAVE * W_CAP; i += 1024) {
            if ((unsigned)(i & (W_CAP - 1)) < wcnt[i >> 9]) {
                u64 e = cl[i];
                if ((unsigned)(e >> 32) == T) {
                    unsigned p_ = atomicAdd(&tn, 1u);
                    if (p_ < 256u) tlist[p_] = (unsigned)e;
                }
            }
        }
    } else {
        for (int i = t; i < HW_N; i += 1024) {
            if (__float_as_uint(mrow[i]) == T) {
                unsigned p_ = atomicAdd(&tn, 1u);
                if (p_ < 256u) tlist[p_] = (unsigned)i;
            }
        }
    }
    __syncthreads();
    if (t == 0) {
        unsigned n2 = (tn < 256u) ? tn : 256u;
        for (unsigned a = 1; a < n2; a++) {
            unsigned key = tlist[a]; int b = (int)a - 1;
            while (b >= 0 && tlist[b] > key) { tlist[b+1] = tlist[b]; b--; }
            tlist[b+1] = key;
        }
        unsigned r = R;
        if (r > n2) r = n2;
        if (r < 1u) r = 1u;
        scut = (n2 > 0u) ? tlist[r - 1] : 0u;
    }
    if (t < NWAVE) wsel[t] = 0u;
    __syncthreads();
    unsigned cut = scut;

    // ---------------- (d) select + gather + write ----------------
    // pass 1: per-wave selected counts
    if (ok) {
        for (int i = t; i < NWAVE * W_CAP; i += 1024) {
            if ((unsigned)(i & (W_CAP - 1)) < wcnt[i >> 9]) {
                u64 e = cl[i];
                unsigned u = (unsigned)(e >> 32), id = (unsigned)e;
                if (u > T || (u == T && id <= cut)) atomicAdd(&wsel[wave], 1u);
            }
        }
    } else {
        for (int i = t; i < HW_N; i += 1024) {
            unsigned u = __float_as_uint(mrow[i]);
            if (u > T || (u == T && (unsigned)i <= cut)) atomicAdd(&wsel[wave], 1u);
        }
    }
    __syncthreads();
    if (t == 0) {
        unsigned run = 0;
#pragma unroll
        for (int c2 = 0; c2 < NWAVE; c2++) { wpos[c2] = run; run += wsel[c2]; }
    }
    __syncthreads();
    // pass 2: write at reserved positions (order-free; downstream order-free)
    if (ok) {
        for (int i = t; i < NWAVE * W_CAP; i += 1024) {
            if ((unsigned)(i & (W_CAP - 1)) < wcnt[i >> 9]) {
                u64 e = cl[i];
                unsigned u = (unsigned)(e >> 32), id = (unsigned)e;
                if (u > T || (u == T && id <= cut)) {
                    unsigned p_ = atomicAdd(&wpos[wave], 1u);
                    if (p_ < K_SEL) {
                        const float* gm = means + ((size_t)row * HW_N + id) * 3;
                        float sx = gm[0], sy = gm[1], sz = gm[2];
                        float sa = fmaf(sx, sx, fmaf(sy, sy, sz * sz));
                        float w  = (u > HALF_BITS) ? sa : -1.0f;
                        sampbuf[(size_t)row * K_SEL + p_] = make_float4(sx, sy, sz, w);
                    }
                }
            }
        }
    } else {
        for (int i = t; i < HW_N; i += 1024) {
            unsigned u = __float_as_uint(mrow[i]);
            if (u > T || (u == T && (unsigned)i <= cut)) {
                unsigned p_ = atomicAdd(&wpos[wave], 1u);
                if (p_ < K_SEL) {
                    const float* gm = means + ((size_t)row * HW_N + i) * 3;
                    float sx = gm[0], sy = gm[1], sz = gm[2];
                    float sa = fmaf(sx, sx, fmaf(sy, sy, sz * sz));
                    float w  = (u > HALF_BITS) ? sa : -1.0f;
                    sampbuf[(size_t)row * K_SEL + p_] = make_float4(sx, sy, sz, w);
                }
            }
        }
    }
}

// ---------------------------------------------------------------------------
// Kernel 2: NN partial mins. 1024 blocks = (row, mesh-slice of 98 points).
// 128 threads; each lane holds 8 samples in regs -> one broadcast LDS read
// serves 512 pairs. No atomics, no fences. (unchanged from R6/R7)
// ---------------------------------------------------------------------------
__global__ void __launch_bounds__(128) dist_kernel(
    const float4* __restrict__ meshP, const float4* __restrict__ sampbuf,
    float* __restrict__ minpart)
{
    __shared__ float4 mq[SLICE];
    int blk = blockIdx.x;
    int r = blk >> 4, sl = blk & 15;
    int t = threadIdx.x;

    if (t < SLICE) mq[t] = meshP[r * NMESH_PAD + sl * SLICE + t];

    const float4* sb = sampbuf + (size_t)r * K_SEL;
    float sx[8], sy[8], sz[8], mn[8];
#pragma unroll
    for (int k = 0; k < 8; k++) {
        float4 s = sb[t + 128*k];
        sx[k] = s.x; sy[k] = s.y; sz[k] = s.z;
        mn[k] = 3.4e38f;
    }
    __syncthreads();

#pragma unroll 2
    for (int i = 0; i < SLICE; i++) {
        float4 a = mq[i];
#pragma unroll
        for (int k = 0; k < 8; k++)
            mn[k] = fminf(mn[k], fmaf(sx[k], a.x, fmaf(sy[k], a.y, fmaf(sz[k], a.z, a.w))));
    }

    float* mp = minpart + ((size_t)r * NSLICE + sl) * K_SEL;
#pragma unroll
    for (int k = 0; k < 8; k++) mp[t + 128*k] = mn[k];
}

// ---------------------------------------------------------------------------
// Kernel 3: per-sample min over 16 slices + per-row fixed-point sum +
// last-of-64 ticket finalize. Integer adds -> order-invariant -> deterministic.
// (unchanged from R7)
// ---------------------------------------------------------------------------
__global__ void __launch_bounds__(256) reduce_kernel(
    const float* __restrict__ minpart, const float4* __restrict__ sampbuf,
    unsigned* __restrict__ ctr, float* __restrict__ out)
{
    __shared__ long long rs[256];
    __shared__ unsigned rc[256];
    int row = blockIdx.x;
    int t = threadIdx.x;

    long long acc = 0; unsigned c = 0;
#pragma unroll
    for (int k = 0; k < 4; k++) {
        int j = k * 256 + t;
        const float* mp = minpart + (size_t)row * NSLICE * K_SEL + j;
        float m = mp[0];
#pragma unroll
        for (int s = 1; s < NSLICE; s++) m = fminf(m, mp[s * (int)K_SEL]);
        float4 sp = sampbuf[(size_t)row * K_SEL + j];
        if (sp.w >= 0.0f) {
            float d2 = fmaxf(m + sp.w, 0.0f);
            acc += (long long)((double)d2 * FIX_SCALE);
            c += 1u;
        }
    }
    rs[t] = acc; rc[t] = c;
    __syncthreads();
    for (int off = 128; off > 0; off >>= 1) {
        if (t < off) { rs[t] += rs[t+off]; rc[t] += rc[t+off]; }
        __syncthreads();
    }
    if (t == 0) {
        atomicAdd((u64*)ctr, (u64)rs[0]);
        atomicAdd(&ctr[2], rc[0]);
        __threadfence();
        unsigned tk = atomicAdd(&ctr[3], 1u);
        if (tk == (unsigned)(NROW - 1)) {
            u64 sbits = atomicAdd((u64*)ctr, 0ull);
            unsigned cc = atomicAdd(&ctr[2], 0u);
            double sum = (double)(long long)sbits / FIX_SCALE;
            out[0] = (float)(sum / (double)(cc ? cc : 1u));
        }
    }
}

extern "C" void kernel_launch(void* const* d_in, const int* in_sizes, int n_in,
                              void* d_out, int out_size, void* d_ws, size_t ws_size,
                              hipStream_t stream) {
    const float* hp    = (const float*)d_in[0];
    const float* means = (const float*)d_in[1];
    const float* mask  = (const float*)d_in[2];
    const int*   hv    = (const int*)  d_in[3];
    const float* vtl   = (const float*)d_in[4];
    const float* vtr   = (const float*)d_in[5];
    const float* sdl   = (const float*)d_in[6];
    const float* sdr   = (const float*)d_in[7];
    const float* pdl   = (const float*)d_in[8];
    const float* pdr   = (const float*)d_in[9];
    float* out = (float*)d_out;

    char* ws = (char*)d_ws;
    float4*   meshP   = (float4*)(ws + OFF_MESH);
    float4*   sampbuf = (float4*)(ws + OFF_SAMP);
    float*    minpart = (float*)(ws + OFF_MINP);
    unsigned* ctr     = (unsigned*)(ws + OFF_CTR);

    prep_kernel<<<NROW, 1024, 0, stream>>>(mask, means, hv, hp,
                                           vtl, vtr, sdl, sdr, pdl, pdr,
                                           meshP, sampbuf, ctr);
    dist_kernel<<<NROW * NSLICE, 128, 0, stream>>>(meshP, sampbuf, minpart);
    reduce_kernel<<<NROW, 256, 0, stream>>>(minpart, sampbuf, ctr, out);
}